// Round 1
// baseline (1997.615 us; speedup 1.0000x reference)
//
#include <hip/hip_runtime.h>

#define NB 256
#define NN 1024
#define ND 64
#define NSTAGES 11
#define EPSF 1e-7f

// Output layout (float32, concatenated):
//   losses (B, 11, N)        at offset 0
//   preds  (B, N, 11, 2)     at PRED_BASE
//   norms  (B, 11, N)        at NORM_BASE
static constexpr size_t PRED_BASE = (size_t)NB * NSTAGES * NN;                 // 2883584
static constexpr size_t NORM_BASE = PRED_BASE + (size_t)NB * NN * NSTAGES * 2; // 8650752

__device__ __forceinline__ void emit_out(float* __restrict__ out, int b, int n, int s,
                                         float z0, float z1, float nrm2, int label) {
  float m  = fmaxf(z0, z1);
  float p0 = expf(z0 - m), p1 = expf(z1 - m);
  float inv = 1.0f / (p0 + p1);
  p0 *= inv; p1 *= inv;
  float pt = label ? p1 : p0;
  pt = fminf(fmaxf(pt, EPSF), 1.0f);
  out[((size_t)b * NSTAGES + s) * NN + n] = -logf(pt);
  size_t pb = PRED_BASE + (((size_t)b * NN + n) * NSTAGES + s) * 2;
  out[pb + 0] = p0;
  out[pb + 1] = p1;
  out[NORM_BASE + ((size_t)b * NSTAGES + s) * NN + n] = sqrtf(nrm2);
}

// Pre-transpose the (64,64) second-layer weights so that for a fixed output
// channel o the 64 weights are contiguous -> s_load_dwordx16-friendly.
__global__ __launch_bounds__(256) void transpose_w2_kernel(
    const float* __restrict__ cn_W2, const float* __restrict__ bn_W2,
    float* __restrict__ cnT, float* __restrict__ bnT) {
  int t = blockIdx.x * 256 + threadIdx.x;   // 4096 threads
  int j = t >> 6, o = t & 63;
  cnT[o * 64 + j] = cn_W2[j * 64 + o];
  bnT[o * 64 + j] = bn_W2[j * 64 + o];
}

// Stage 0: e = y @ emb_W + emb_b ; v = x ; emit llr/loss/norm for stage idx 0.
// One lane per (b,n) position; lane-local 64-channel row kept in flight 4 at a time.
__global__ __launch_bounds__(64) void stage0_kernel(
    const int* __restrict__ x, const float* __restrict__ y,
    const float* __restrict__ emb_W, const float* __restrict__ emb_b,
    const float* __restrict__ llr_W, const float* __restrict__ llr_b,
    float* __restrict__ e_out, int* __restrict__ v_out, float* __restrict__ out) {
  int pos = blockIdx.x * 64 + threadIdx.x;       // [0, B*N)
  int b = pos >> 10, n = pos & (NN - 1);
  float y0 = y[(size_t)pos * 2 + 0];
  float y1 = y[(size_t)pos * 2 + 1];
  float z0 = llr_b[0], z1 = llr_b[1], nrm = 0.0f;
  float* erow = e_out + (size_t)pos * ND;
  for (int o4 = 0; o4 < 16; ++o4) {
    float4 av;
    #pragma unroll
    for (int t = 0; t < 4; ++t) {
      int o = o4 * 4 + t;
      float ev = fmaf(y0, emb_W[o], fmaf(y1, emb_W[64 + o], emb_b[o]));
      ((float*)&av)[t] = ev;
      z0 = fmaf(ev, llr_W[o * 2 + 0], z0);
      z1 = fmaf(ev, llr_W[o * 2 + 1], z1);
      nrm = fmaf(ev, ev, nrm);
    }
    *(float4*)(erow + o4 * 4) = av;
  }
  int v = x[pos] & 1;
  v_out[pos] = v;
  emit_out(out, b, n, 0, z0, z1, nrm, v);
}

// One polar stage. One lane per pair (64 pairs per 1-wave block).
// Hidden activations h[64] live in VGPRs (all indexing via fully-unrolled loops);
// weights are lane-uniform -> scalar loads (SGPR broadcast), so the inner loop is
// pure v_fmac_f32 with no per-FMA vector-memory traffic.
__global__ __launch_bounds__(64) void stage_kernel(
    const float* __restrict__ e_in, float* __restrict__ e_out,
    const int* __restrict__ v_in, int* __restrict__ v_out,
    const float* __restrict__ cn_W1, const float* __restrict__ cn_b1,
    const float* __restrict__ cn_W2T, const float* __restrict__ cn_b2,
    const float* __restrict__ bn_W1, const float* __restrict__ bn_b1,
    const float* __restrict__ bn_W2T, const float* __restrict__ bn_b2,
    const float* __restrict__ lab_emb,
    const float* __restrict__ llr_W, const float* __restrict__ llr_b,
    float* __restrict__ out, int scope, int log_half, int sIdx) {
  int p = blockIdx.x * 64 + threadIdx.x;   // pair index in [0, B*N/2)
  int b = p >> 9;                          // / (N/2)
  int i = p & 511;
  int half = scope >> 1;
  int k = i >> log_half;
  int q = i & (half - 1);
  int row = b << 10;                       // b * N
  int idx_o = k * scope + q;
  int idx_e = idx_o + half;
  const float* eo = e_in + (size_t)(row + idx_o) * ND;
  const float* ee = e_in + (size_t)(row + idx_e) * ND;
  int vo = v_in[row + idx_o] & 1;
  int ve = v_in[row + idx_e] & 1;
  int vx = vo ^ ve;
  const float* lemb = lab_emb + vx * ND;

  int n_l = 2 * i, n_r = 2 * i + 1;
  v_out[row + n_l] = vx;
  v_out[row + n_r] = ve;

  float h[64];

  // ===================== cn: relu([eo;ee] @ W1 + b1) @ W2 + b2 ==============
  #pragma unroll
  for (int j = 0; j < 64; ++j) h[j] = cn_b1[j];
  for (int c = 0; c < 16; ++c) {
    float4 xa = *(const float4*)(eo + c * 4);
    float4 xb = *(const float4*)(ee + c * 4);
    #pragma unroll
    for (int t = 0; t < 4; ++t) {
      float va = ((const float*)&xa)[t];
      float vb = ((const float*)&xb)[t];
      int d = c * 4 + t;
      #pragma unroll
      for (int j = 0; j < 64; ++j) {
        h[j] = fmaf(va, cn_W1[(d)      * 64 + j], h[j]);
        h[j] = fmaf(vb, cn_W1[(64 + d) * 64 + j], h[j]);
      }
    }
  }
  #pragma unroll
  for (int j = 0; j < 64; ++j) h[j] = fmaxf(h[j], 0.0f);

  {
    float z0 = llr_b[0], z1 = llr_b[1], nrm = 0.0f;
    float* orow = e_out + (size_t)(row + n_l) * ND;
    for (int o4 = 0; o4 < 16; ++o4) {
      float4 av;
      #pragma unroll
      for (int t = 0; t < 4; ++t) {
        int o = o4 * 4 + t;
        float acc = cn_b2[o];
        const float* wrow = cn_W2T + o * 64;
        #pragma unroll
        for (int j = 0; j < 64; ++j) acc = fmaf(h[j], wrow[j], acc);
        ((float*)&av)[t] = acc;
        z0 = fmaf(acc, llr_W[o * 2 + 0], z0);
        z1 = fmaf(acc, llr_W[o * 2 + 1], z1);
        nrm = fmaf(acc, acc, nrm);
      }
      *(float4*)(orow + o4 * 4) = av;
    }
    emit_out(out, b, n_l, sIdx, z0, z1, nrm, vx);
  }

  // ============ bn: relu([eo;ee;lab_emb[vx]] @ W1 + b1) @ W2 + b2 ===========
  #pragma unroll
  for (int j = 0; j < 64; ++j) h[j] = bn_b1[j];
  for (int c = 0; c < 16; ++c) {
    float4 xa = *(const float4*)(eo + c * 4);
    float4 xb = *(const float4*)(ee + c * 4);
    float4 xc = *(const float4*)(lemb + c * 4);
    #pragma unroll
    for (int t = 0; t < 4; ++t) {
      float va = ((const float*)&xa)[t];
      float vb = ((const float*)&xb)[t];
      float vc = ((const float*)&xc)[t];
      int d = c * 4 + t;
      #pragma unroll
      for (int j = 0; j < 64; ++j) {
        h[j] = fmaf(va, bn_W1[(d)       * 64 + j], h[j]);
        h[j] = fmaf(vb, bn_W1[(64 + d)  * 64 + j], h[j]);
        h[j] = fmaf(vc, bn_W1[(128 + d) * 64 + j], h[j]);
      }
    }
  }
  #pragma unroll
  for (int j = 0; j < 64; ++j) h[j] = fmaxf(h[j], 0.0f);

  {
    float z0 = llr_b[0], z1 = llr_b[1], nrm = 0.0f;
    float* orow = e_out + (size_t)(row + n_r) * ND;
    for (int o4 = 0; o4 < 16; ++o4) {
      float4 av;
      #pragma unroll
      for (int t = 0; t < 4; ++t) {
        int o = o4 * 4 + t;
        float acc = bn_b2[o];
        const float* wrow = bn_W2T + o * 64;
        #pragma unroll
        for (int j = 0; j < 64; ++j) acc = fmaf(h[j], wrow[j], acc);
        ((float*)&av)[t] = acc;
        z0 = fmaf(acc, llr_W[o * 2 + 0], z0);
        z1 = fmaf(acc, llr_W[o * 2 + 1], z1);
        nrm = fmaf(acc, acc, nrm);
      }
      *(float4*)(orow + o4 * 4) = av;
    }
    emit_out(out, b, n_r, sIdx, z0, z1, nrm, ve);
  }
}

extern "C" void kernel_launch(void* const* d_in, const int* in_sizes, int n_in,
                              void* d_out, int out_size, void* d_ws, size_t ws_size,
                              hipStream_t stream) {
  const int*   x      = (const int*)d_in[0];
  const float* y      = (const float*)d_in[1];
  const float* emb_W  = (const float*)d_in[2];
  const float* emb_b  = (const float*)d_in[3];
  const float* labemb = (const float*)d_in[4];
  const float* cn_W1  = (const float*)d_in[5];
  const float* cn_b1  = (const float*)d_in[6];
  const float* cn_W2  = (const float*)d_in[7];
  const float* cn_b2  = (const float*)d_in[8];
  const float* bn_W1  = (const float*)d_in[9];
  const float* bn_b1  = (const float*)d_in[10];
  const float* bn_W2  = (const float*)d_in[11];
  const float* bn_b2  = (const float*)d_in[12];
  const float* llr_W  = (const float*)d_in[13];
  const float* llr_b  = (const float*)d_in[14];
  float* out = (float*)d_out;

  char* ws = (char*)d_ws;
  size_t e_bytes = (size_t)NB * NN * ND * sizeof(float);   // 64 MB
  size_t v_bytes = (size_t)NB * NN * sizeof(int);          // 1 MB
  float* e0 = (float*)(ws);
  float* e1 = (float*)(ws + e_bytes);
  int*   v0 = (int*)(ws + 2 * e_bytes);
  int*   v1 = (int*)(ws + 2 * e_bytes + v_bytes);
  float* cn_W2T = (float*)(ws + 2 * e_bytes + 2 * v_bytes);
  float* bn_W2T = cn_W2T + 64 * 64;

  transpose_w2_kernel<<<16, 256, 0, stream>>>(cn_W2, bn_W2, cn_W2T, bn_W2T);
  stage0_kernel<<<(NB * NN) / 64, 64, 0, stream>>>(x, y, emb_W, emb_b, llr_W, llr_b,
                                                   e0, v0, out);

  float* ein = e0; float* eout = e1;
  int* vin = v0;  int* vout = v1;
  int scope = 2;
  for (int s = 1; s <= 10; ++s) {
    int log_half = s - 1;
    stage_kernel<<<(NB * NN / 2) / 64, 64, 0, stream>>>(
        ein, eout, vin, vout,
        cn_W1, cn_b1, cn_W2T, cn_b2,
        bn_W1, bn_b1, bn_W2T, bn_b2,
        labemb, llr_W, llr_b, out, scope, log_half, s);
    float* te = ein; ein = eout; eout = te;
    int* tv = vin; vin = vout; vout = tv;
    scope <<= 1;
  }
}

// Round 2
// 458.142 us; speedup vs baseline: 4.3603x; 4.3603x over previous
//
#include <hip/hip_runtime.h>

#define NB 256
#define NN 1024
#define NSTAGES 11
#define EPSF 1e-7f

typedef unsigned short u16;
typedef __attribute__((ext_vector_type(8))) short short8;
typedef __attribute__((ext_vector_type(4))) float f32x4;

// Output layout (float32, concatenated):
//   losses (B, 11, N); preds (B, N, 11, 2); norms (B, 11, N)
static constexpr size_t PRED_BASE = (size_t)NB * NSTAGES * NN;
static constexpr size_t NORM_BASE = PRED_BASE + (size_t)NB * NN * NSTAGES * 2;

// wfrag layout (u16 units): 56 B-fragments of [64 lanes][8 bf16] + bf16 lab_emb
//   cn_W1 frags [ks<4][nt<4]   at 0      (frag ids  0..15)
//   bn_W1 frags [ks<6][nt<4]   at 8192   (frag ids 16..39)
//   cn_W2 frags [ks<2][nt<4]   at 20480  (frag ids 40..47)
//   bn_W2 frags [ks<2][nt<4]   at 24576  (frag ids 48..55)
//   lab_emb bf16 (2x64)        at 28672
static constexpr int LAB_OFF = 28672;

__device__ __forceinline__ u16 f2bf(float f) {
  unsigned u = __float_as_uint(f);
  unsigned r = (u + 0x7fffu + ((u >> 16) & 1u)) >> 16;
  return (u16)r;
}

__device__ __forceinline__ float red16(float v) {
  v += __shfl_xor(v, 1, 16);
  v += __shfl_xor(v, 2, 16);
  v += __shfl_xor(v, 4, 16);
  v += __shfl_xor(v, 8, 16);
  return v;
}

__device__ __forceinline__ void emit_out(float* __restrict__ out, int b, int n, int s,
                                         float z0, float z1, float nrm2, int label) {
  float m  = fmaxf(z0, z1);
  float p0 = expf(z0 - m), p1 = expf(z1 - m);
  float inv = 1.0f / (p0 + p1);
  p0 *= inv; p1 *= inv;
  float pt = label ? p1 : p0;
  pt = fminf(fmaxf(pt, EPSF), 1.0f);
  out[((size_t)b * NSTAGES + s) * NN + n] = -logf(pt);
  size_t pb = PRED_BASE + (((size_t)b * NN + n) * NSTAGES + s) * 2;
  out[pb + 0] = p0;
  out[pb + 1] = p1;
  out[NORM_BASE + ((size_t)b * NSTAGES + s) * NN + n] = sqrtf(nrm2);
}

// Pack all weights into MFMA B-operand fragment order (bf16):
// B[k][n] held by lane l as element j with n = (l&15)+nt*16, k = ks*32+(l>>4)*8+j.
__global__ __launch_bounds__(256) void prep_kernel(
    const float* __restrict__ cn_W1, const float* __restrict__ bn_W1,
    const float* __restrict__ cn_W2, const float* __restrict__ bn_W2,
    const float* __restrict__ lab_emb, u16* __restrict__ wfrag) {
  int t = blockIdx.x * 256 + threadIdx.x;
  if (t < 3584) {
    int f = t >> 6, lane = t & 63, q = lane >> 4, n15 = lane & 15;
    const float* src; int kbase, col;
    if (f < 16)      { src = cn_W1; kbase = (f >> 2) * 32; col = (f & 3) * 16 + n15; }
    else if (f < 40) { int g = f - 16; src = bn_W1; kbase = (g >> 2) * 32; col = (g & 3) * 16 + n15; }
    else if (f < 48) { int g = f - 40; src = cn_W2; kbase = (g >> 2) * 32; col = (g & 3) * 16 + n15; }
    else             { int g = f - 48; src = bn_W2; kbase = (g >> 2) * 32; col = (g & 3) * 16 + n15; }
    u16 vals[8];
    #pragma unroll
    for (int j = 0; j < 8; ++j) {
      int k = kbase + q * 8 + j;
      vals[j] = f2bf(src[k * 64 + col]);
    }
    uint4 u;
    u.x = (unsigned)vals[0] | ((unsigned)vals[1] << 16);
    u.y = (unsigned)vals[2] | ((unsigned)vals[3] << 16);
    u.z = (unsigned)vals[4] | ((unsigned)vals[5] << 16);
    u.w = (unsigned)vals[6] | ((unsigned)vals[7] << 16);
    *(uint4*)(wfrag + (size_t)t * 8) = u;
  } else if (t < 3584 + 128) {
    wfrag[LAB_OFF + (t - 3584)] = f2bf(lab_emb[t - 3584]);
  }
}

// Stage 0: e = y @ emb_W + emb_b (K=2, vector path); store e as bf16.
__global__ __launch_bounds__(256) void stage0_kernel(
    const int* __restrict__ x, const float* __restrict__ y,
    const float* __restrict__ emb_W, const float* __restrict__ emb_b,
    const float* __restrict__ llr_W, const float* __restrict__ llr_b,
    u16* __restrict__ e_out, int* __restrict__ v_out, float* __restrict__ out) {
  int pos = blockIdx.x * 256 + threadIdx.x;     // [0, B*N)
  int b = pos >> 10, n = pos & (NN - 1);
  float y0 = y[(size_t)pos * 2 + 0];
  float y1 = y[(size_t)pos * 2 + 1];
  float z0 = llr_b[0], z1 = llr_b[1], nrm = 0.0f;
  u16* erow = e_out + (size_t)pos * 64;
  for (int o8 = 0; o8 < 8; ++o8) {
    u16 vals[8];
    #pragma unroll
    for (int j = 0; j < 8; ++j) {
      int o = o8 * 8 + j;
      float ev = fmaf(y0, emb_W[o], fmaf(y1, emb_W[64 + o], emb_b[o]));
      vals[j] = f2bf(ev);
      z0 = fmaf(ev, llr_W[o * 2 + 0], z0);
      z1 = fmaf(ev, llr_W[o * 2 + 1], z1);
      nrm = fmaf(ev, ev, nrm);
    }
    uint4 u;
    u.x = (unsigned)vals[0] | ((unsigned)vals[1] << 16);
    u.y = (unsigned)vals[2] | ((unsigned)vals[3] << 16);
    u.z = (unsigned)vals[4] | ((unsigned)vals[5] << 16);
    u.w = (unsigned)vals[6] | ((unsigned)vals[7] << 16);
    *(uint4*)(erow + o8 * 8) = u;
  }
  int v = x[pos] & 1;
  v_out[pos] = v;
  emit_out(out, b, n, 0, z0, z1, nrm, v);
}

// One polar stage via MFMA. 256 threads = 4 waves; each wave owns a tile of
// 16 pairs x 64 channels. Both MLPs (cn K=128, bn K=192) share A-fragments.
// A layout: m=lane&15, k=quad*8+j; C/D: col=lane&15, row=quad*4+reg.
// Layer1->Layer2 transpose via per-wave private LDS (stride 72 u16: 2-way banks).
__global__ __launch_bounds__(256, 4) void stage_mfma_kernel(
    const u16* __restrict__ e_in, u16* __restrict__ e_out,
    const int* __restrict__ v_in, int* __restrict__ v_out,
    const u16* __restrict__ wfrag,
    const float* __restrict__ cn_b1, const float* __restrict__ cn_b2,
    const float* __restrict__ bn_b1, const float* __restrict__ bn_b2,
    const float* __restrict__ llr_W, const float* __restrict__ llr_b,
    float* __restrict__ out, int sIdx) {
  __shared__ __align__(16) u16 hbuf[4][2][16 * 72];
  int tid = threadIdx.x;
  int wid = tid >> 6, ln = tid & 63, quad = ln >> 4, ln15 = ln & 15;
  int tile = blockIdx.x * 4 + wid;     // [0, 8192)
  int P0 = tile << 4;                  // base pair index
  int b = P0 >> 9, i0 = P0 & 511;
  int rowb = b << 10;
  int log_half = sIdx - 1, half = 1 << log_half, scope = half << 1;

  // this lane's A-row pair (m = ln15)
  int im = i0 + ln15;
  int g = im >> log_half, u = im & (half - 1);
  int idx_o = g * scope + u, idx_e = idx_o + half;
  const u16* eo = e_in + (size_t)(rowb + idx_o) * 64;
  const u16* ee = e_in + (size_t)(rowb + idx_e) * 64;
  int vo = v_in[rowb + idx_o] & 1;
  int ve = v_in[rowb + idx_e] & 1;
  int vx = vo ^ ve;

  short8 ae[4];
  ae[0] = *(const short8*)(eo + quad * 8);
  ae[1] = *(const short8*)(eo + 32 + quad * 8);
  ae[2] = *(const short8*)(ee + quad * 8);
  ae[3] = *(const short8*)(ee + 32 + quad * 8);
  const u16* lf = wfrag + LAB_OFF + vx * 64;
  short8 aL0 = *(const short8*)(lf + quad * 8);
  short8 aL1 = *(const short8*)(lf + 32 + quad * 8);

  const short8* wp = (const short8*)wfrag;

  float cb1[4], bb1[4], cb2[4], bb2[4], lw0[4], lw1[4];
  #pragma unroll
  for (int nt = 0; nt < 4; ++nt) {
    int c = nt * 16 + ln15;
    cb1[nt] = cn_b1[c]; bb1[nt] = bn_b1[c];
    cb2[nt] = cn_b2[c]; bb2[nt] = bn_b2[c];
    lw0[nt] = llr_W[c * 2 + 0]; lw1[nt] = llr_W[c * 2 + 1];
  }
  float lb0 = llr_b[0], lb1 = llr_b[1];

  // ---- layer 1 ----
  f32x4 aC[4], aB[4];
  #pragma unroll
  for (int nt = 0; nt < 4; ++nt) {
    aC[nt] = (f32x4){cb1[nt], cb1[nt], cb1[nt], cb1[nt]};
    aB[nt] = (f32x4){bb1[nt], bb1[nt], bb1[nt], bb1[nt]};
  }
  #pragma unroll
  for (int ks = 0; ks < 4; ++ks) {
    #pragma unroll
    for (int nt = 0; nt < 4; ++nt) {
      aC[nt] = __builtin_amdgcn_mfma_f32_16x16x32_bf16(ae[ks], wp[(ks * 4 + nt) * 64 + ln], aC[nt], 0, 0, 0);
      aB[nt] = __builtin_amdgcn_mfma_f32_16x16x32_bf16(ae[ks], wp[(16 + ks * 4 + nt) * 64 + ln], aB[nt], 0, 0, 0);
    }
  }
  #pragma unroll
  for (int nt = 0; nt < 4; ++nt) {
    aB[nt] = __builtin_amdgcn_mfma_f32_16x16x32_bf16(aL0, wp[(16 + 16 + nt) * 64 + ln], aB[nt], 0, 0, 0);
    aB[nt] = __builtin_amdgcn_mfma_f32_16x16x32_bf16(aL1, wp[(16 + 20 + nt) * 64 + ln], aB[nt], 0, 0, 0);
  }

  // ---- relu -> bf16 -> LDS (C/D layout -> A layout transpose) ----
  u16* hc = &hbuf[wid][0][0];
  u16* hb = &hbuf[wid][1][0];
  #pragma unroll
  for (int nt = 0; nt < 4; ++nt) {
    #pragma unroll
    for (int r = 0; r < 4; ++r) {
      int row = quad * 4 + r, col = nt * 16 + ln15;
      hc[row * 72 + col] = f2bf(fmaxf(aC[nt][r], 0.0f));
      hb[row * 72 + col] = f2bf(fmaxf(aB[nt][r], 0.0f));
    }
  }

  // ---- layer 2 ----
  f32x4 dC[4], dB[4];
  #pragma unroll
  for (int nt = 0; nt < 4; ++nt) {
    dC[nt] = (f32x4){cb2[nt], cb2[nt], cb2[nt], cb2[nt]};
    dB[nt] = (f32x4){bb2[nt], bb2[nt], bb2[nt], bb2[nt]};
  }
  #pragma unroll
  for (int ks = 0; ks < 2; ++ks) {
    short8 hAc = *(const short8*)(hc + ln15 * 72 + ks * 32 + quad * 8);
    short8 hAb = *(const short8*)(hb + ln15 * 72 + ks * 32 + quad * 8);
    #pragma unroll
    for (int nt = 0; nt < 4; ++nt) {
      dC[nt] = __builtin_amdgcn_mfma_f32_16x16x32_bf16(hAc, wp[(40 + ks * 4 + nt) * 64 + ln], dC[nt], 0, 0, 0);
      dB[nt] = __builtin_amdgcn_mfma_f32_16x16x32_bf16(hAb, wp[(48 + ks * 4 + nt) * 64 + ln], dB[nt], 0, 0, 0);
    }
  }

  // ---- v propagation ----
  if (quad == 0) {
    v_out[rowb + 2 * im + 0] = vx;
    v_out[rowb + 2 * im + 1] = ve;
  }

  // ---- epilogue: cn outputs at n = 2*i (label vx) ----
  #pragma unroll
  for (int r = 0; r < 4; ++r) {
    int row = quad * 4 + r;
    int n = 2 * (i0 + row);
    float z0 = 0.f, z1 = 0.f, nr = 0.f;
    #pragma unroll
    for (int nt = 0; nt < 4; ++nt) {
      float v = dC[nt][r];
      z0 = fmaf(v, lw0[nt], z0);
      z1 = fmaf(v, lw1[nt], z1);
      nr = fmaf(v, v, nr);
      e_out[(size_t)(rowb + n) * 64 + nt * 16 + ln15] = f2bf(v);
    }
    z0 = red16(z0) + lb0;
    z1 = red16(z1) + lb1;
    nr = red16(nr);
    if (ln15 == row) emit_out(out, b, n, sIdx, z0, z1, nr, vx);
  }

  // ---- epilogue: bn outputs at n = 2*i+1 (label ve) ----
  #pragma unroll
  for (int r = 0; r < 4; ++r) {
    int row = quad * 4 + r;
    int n = 2 * (i0 + row) + 1;
    float z0 = 0.f, z1 = 0.f, nr = 0.f;
    #pragma unroll
    for (int nt = 0; nt < 4; ++nt) {
      float v = dB[nt][r];
      z0 = fmaf(v, lw0[nt], z0);
      z1 = fmaf(v, lw1[nt], z1);
      nr = fmaf(v, v, nr);
      e_out[(size_t)(rowb + n) * 64 + nt * 16 + ln15] = f2bf(v);
    }
    z0 = red16(z0) + lb0;
    z1 = red16(z1) + lb1;
    nr = red16(nr);
    if (ln15 == row) emit_out(out, b, n, sIdx, z0, z1, nr, ve);
  }
}

extern "C" void kernel_launch(void* const* d_in, const int* in_sizes, int n_in,
                              void* d_out, int out_size, void* d_ws, size_t ws_size,
                              hipStream_t stream) {
  const int*   x      = (const int*)d_in[0];
  const float* y      = (const float*)d_in[1];
  const float* emb_W  = (const float*)d_in[2];
  const float* emb_b  = (const float*)d_in[3];
  const float* labemb = (const float*)d_in[4];
  const float* cn_W1  = (const float*)d_in[5];
  const float* cn_b1  = (const float*)d_in[6];
  const float* cn_W2  = (const float*)d_in[7];
  const float* cn_b2  = (const float*)d_in[8];
  const float* bn_W1  = (const float*)d_in[9];
  const float* bn_b1  = (const float*)d_in[10];
  const float* bn_W2  = (const float*)d_in[11];
  const float* bn_b2  = (const float*)d_in[12];
  const float* llr_W  = (const float*)d_in[13];
  const float* llr_b  = (const float*)d_in[14];
  float* out = (float*)d_out;

  char* ws = (char*)d_ws;
  size_t e_bytes = (size_t)NB * NN * 64 * sizeof(u16);     // 32 MB
  size_t v_bytes = (size_t)NB * NN * sizeof(int);          // 1 MB
  u16* e0 = (u16*)(ws);
  u16* e1 = (u16*)(ws + e_bytes);
  int* v0 = (int*)(ws + 2 * e_bytes);
  int* v1 = (int*)(ws + 2 * e_bytes + v_bytes);
  u16* wfrag = (u16*)(ws + 2 * e_bytes + 2 * v_bytes);

  prep_kernel<<<15, 256, 0, stream>>>(cn_W1, bn_W1, cn_W2, bn_W2, labemb, wfrag);
  stage0_kernel<<<NB * NN / 256, 256, 0, stream>>>(x, y, emb_W, emb_b, llr_W, llr_b,
                                                   e0, v0, out);

  u16* ein = e0; u16* eout = e1;
  int* vin = v0; int* vout = v1;
  for (int s = 1; s <= 10; ++s) {
    stage_mfma_kernel<<<2048, 256, 0, stream>>>(
        ein, eout, vin, vout, wfrag,
        cn_b1, cn_b2, bn_b1, bn_b2, llr_W, llr_b, out, s);
    u16* te = ein; ein = eout; eout = te;
    int* tv = vin; vin = vout; vout = tv;
  }
}

// Round 3
// 379.980 us; speedup vs baseline: 5.2572x; 1.2057x over previous
//
#include <hip/hip_runtime.h>

#define NB 256
#define NN 1024
#define NSTAGES 11
#define EPSF 1e-7f

typedef unsigned short u16;
typedef __attribute__((ext_vector_type(8))) short short8;
typedef __attribute__((ext_vector_type(16))) float f32x16;

// Output layout (float32, concatenated):
//   losses (B, 11, N); preds (B, N, 11, 2); norms (B, 11, N)
static constexpr size_t PRED_BASE = (size_t)NB * NSTAGES * NN;
static constexpr size_t NORM_BASE = PRED_BASE + (size_t)NB * NN * NSTAGES * 2;

// wfrag layout (u16 units), B-fragments for mfma_f32_32x32x16_bf16:
//   frag fi: [64 lanes][8 bf16], value B[k][n]: n = nt*32+(lane&31),
//   k = ks*16 + (lane>>5)*8 + j.
//   cn_W1: fi = ks*2+nt        (0..15)   K=128
//   bn_W1: fi = 16 + ks*2+nt   (16..39)  K=192
//   cn_W2: fi = 40 + ks*2+nt   (40..47)  K=64
//   bn_W2: fi = 48 + ks*2+nt   (48..55)  K=64
//   llr_W packed bf16 pairs (u32[64]) at u16 offset 28672
//   lab_emb bf16 (2x64)               at u16 offset 28800
static constexpr int LW_OFF  = 28672;
static constexpr int LAB_OFF = 28800;
static constexpr int LDS_FRAGS = 25;   // frags 0..24 staged in LDS, rest from L1

__device__ __forceinline__ u16 f2bf(float f) {
  unsigned u = __float_as_uint(f);
  unsigned r = (u + 0x7fffu + ((u >> 16) & 1u)) >> 16;
  return (u16)r;
}

__device__ __forceinline__ void emit_out(float* __restrict__ out, int b, int n, int s,
                                         float z0, float z1, float nrm2, int label) {
  float m  = fmaxf(z0, z1);
  float p0 = expf(z0 - m), p1 = expf(z1 - m);
  float inv = 1.0f / (p0 + p1);
  p0 *= inv; p1 *= inv;
  float pt = label ? p1 : p0;
  pt = fminf(fmaxf(pt, EPSF), 1.0f);
  out[((size_t)b * NSTAGES + s) * NN + n] = -logf(pt);
  size_t pb = PRED_BASE + (((size_t)b * NN + n) * NSTAGES + s) * 2;
  out[pb + 0] = p0;
  out[pb + 1] = p1;
  out[NORM_BASE + ((size_t)b * NSTAGES + s) * NN + n] = sqrtf(nrm2);
}

__global__ __launch_bounds__(256) void prep_kernel(
    const float* __restrict__ cn_W1, const float* __restrict__ bn_W1,
    const float* __restrict__ cn_W2, const float* __restrict__ bn_W2,
    const float* __restrict__ lab_emb, const float* __restrict__ llr_W,
    u16* __restrict__ wfrag) {
  int t = blockIdx.x * 256 + threadIdx.x;
  if (t < 3584) {
    int f = t >> 6, l = t & 63, h = l >> 5, c = l & 31;
    const float* src; int ks, nt;
    if (f < 16)      { src = cn_W1; ks = f >> 1; nt = f & 1; }
    else if (f < 40) { int g = f - 16; src = bn_W1; ks = g >> 1; nt = g & 1; }
    else if (f < 48) { int g = f - 40; src = cn_W2; ks = g >> 1; nt = g & 1; }
    else             { int g = f - 48; src = bn_W2; ks = g >> 1; nt = g & 1; }
    int col = nt * 32 + c;
    u16 vals[8];
    #pragma unroll
    for (int j = 0; j < 8; ++j) {
      int k = ks * 16 + h * 8 + j;
      vals[j] = f2bf(src[k * 64 + col]);
    }
    uint4 u;
    u.x = (unsigned)vals[0] | ((unsigned)vals[1] << 16);
    u.y = (unsigned)vals[2] | ((unsigned)vals[3] << 16);
    u.z = (unsigned)vals[4] | ((unsigned)vals[5] << 16);
    u.w = (unsigned)vals[6] | ((unsigned)vals[7] << 16);
    *(uint4*)(wfrag + (size_t)t * 8) = u;
  } else if (t < 3648) {
    int k = t - 3584;
    unsigned w = (unsigned)f2bf(llr_W[k * 2]) | ((unsigned)f2bf(llr_W[k * 2 + 1]) << 16);
    ((unsigned*)(wfrag + LW_OFF))[k] = w;
  } else if (t < 3776) {
    int i = t - 3648;
    wfrag[LAB_OFF + i] = f2bf(lab_emb[i]);
  }
}

// Stage 0: e = y @ emb_W + emb_b (K=2, vector path); store e as bf16; emit s=0.
__global__ __launch_bounds__(256) void stage0_kernel(
    const int* __restrict__ x, const float* __restrict__ y,
    const float* __restrict__ emb_W, const float* __restrict__ emb_b,
    const float* __restrict__ llr_W, const float* __restrict__ llr_b,
    u16* __restrict__ e_out, int* __restrict__ v_out, float* __restrict__ out) {
  int pos = blockIdx.x * 256 + threadIdx.x;     // [0, B*N)
  int b = pos >> 10, n = pos & (NN - 1);
  float y0 = y[(size_t)pos * 2 + 0];
  float y1 = y[(size_t)pos * 2 + 1];
  float z0 = llr_b[0], z1 = llr_b[1], nrm = 0.0f;
  u16* erow = e_out + (size_t)pos * 64;
  for (int o8 = 0; o8 < 8; ++o8) {
    u16 vals[8];
    #pragma unroll
    for (int j = 0; j < 8; ++j) {
      int o = o8 * 8 + j;
      float ev = fmaf(y0, emb_W[o], fmaf(y1, emb_W[64 + o], emb_b[o]));
      vals[j] = f2bf(ev);
      z0 = fmaf(ev, llr_W[o * 2 + 0], z0);
      z1 = fmaf(ev, llr_W[o * 2 + 1], z1);
      nrm = fmaf(ev, ev, nrm);
    }
    uint4 u;
    u.x = (unsigned)vals[0] | ((unsigned)vals[1] << 16);
    u.y = (unsigned)vals[2] | ((unsigned)vals[3] << 16);
    u.z = (unsigned)vals[4] | ((unsigned)vals[5] << 16);
    u.w = (unsigned)vals[6] | ((unsigned)vals[7] << 16);
    *(uint4*)(erow + o8 * 8) = u;
  }
  int v = x[pos] & 1;
  v_out[pos] = v;
  emit_out(out, b, n, 0, z0, z1, nrm, v);
}

// B-fragment fetch: compile-time id -> LDS or global (folds after unroll).
#define BFRAG(FI) (((FI) < LDS_FRAGS) ? *(const short8*)(wlds + (FI) * 512 + ln * 8) \
                                      : *(const short8*)(wfrag + (size_t)(FI) * 512 + ln * 8))

// One polar stage. 256 threads = 4 waves; each wave = one 32-pair tile via
// mfma_f32_32x32x16_bf16.  A: m=lane&31, k=(lane>>5)*8+j;
// C/D: col=lane&31 (+nt*32), row=(reg&3)+8*(reg>>2)+4*(lane>>5).
// Epilogue for stage sIdx-1 is piggybacked on the input rows (each e row is
// read exactly once across the grid).
__global__ __launch_bounds__(256, 2) void stage32_kernel(
    const u16* __restrict__ e_in, u16* __restrict__ e_out,
    const int* __restrict__ v_in, int* __restrict__ v_out,
    const u16* __restrict__ wfrag,
    const float* __restrict__ cn_b1, const float* __restrict__ bn_b1,
    const float* __restrict__ cn_b2, const float* __restrict__ bn_b2,
    const float* __restrict__ llr_b,
    float* __restrict__ out, int sIdx) {
  __shared__ __align__(16) u16 wlds[LDS_FRAGS * 512];
  __shared__ __align__(16) u16 hbuf[4][32 * 72];
  int tid = threadIdx.x;
  {
    const uint4* src = (const uint4*)wfrag;
    uint4* dst = (uint4*)wlds;
    for (int i = tid; i < LDS_FRAGS * 64; i += 256) dst[i] = src[i];
  }
  __syncthreads();

  int ln = tid & 63, wid = tid >> 6;
  int m31 = ln & 31, h8 = ln >> 5;
  int tile = blockIdx.x * 4 + wid;      // [0, 4096)
  int P0 = tile << 5;                   // base pair index
  int b = P0 >> 9, i0 = P0 & 511;
  int rowb = b << 10;
  int log_half = sIdx - 1, half = 1 << log_half;

  int im = i0 + m31;
  int g = im >> log_half, u = im & (half - 1);
  int idx_o = g * (half << 1) + u, idx_e = idx_o + half;
  const u16* eo = e_in + (size_t)(rowb + idx_o) * 64;
  const u16* ee = e_in + (size_t)(rowb + idx_e) * 64;
  int vo = v_in[rowb + idx_o] & 1;
  int ve = v_in[rowb + idx_e] & 1;
  int vx = vo ^ ve;

  short8 aeo[4], aee[4], alab[4];
  #pragma unroll
  for (int f = 0; f < 4; ++f) {
    aeo[f] = *(const short8*)(eo + f * 16 + h8 * 8);
    aee[f] = *(const short8*)(ee + f * 16 + h8 * 8);
  }
  const u16* labT = wfrag + LAB_OFF + vx * 64;
  #pragma unroll
  for (int f = 0; f < 4; ++f) alab[f] = *(const short8*)(labT + f * 16 + h8 * 8);

  if (h8 == 0) {
    v_out[rowb + 2 * im + 0] = vx;
    v_out[rowb + 2 * im + 1] = ve;
  }

  // ---- piggybacked epilogue for stage sIdx-1 on the input rows ----
  if (sIdx >= 2) {
    const unsigned* lwp = (const unsigned*)(wfrag + LW_OFF);
    float lb0 = llr_b[0], lb1 = llr_b[1];
    #pragma unroll
    for (int side = 0; side < 2; ++side) {
      float z0 = 0.f, z1 = 0.f, nr = 0.f;
      #pragma unroll
      for (int f = 0; f < 4; ++f) {
        short8 av8 = side ? aee[f] : aeo[f];
        uint4 q0 = *(const uint4*)(lwp + f * 16 + h8 * 8);
        uint4 q1 = *(const uint4*)(lwp + f * 16 + h8 * 8 + 4);
        #pragma unroll
        for (int j = 0; j < 8; ++j) {
          unsigned pv = ((const unsigned*)&av8)[j >> 1];
          float val = __uint_as_float((j & 1) ? (pv & 0xffff0000u) : (pv << 16));
          unsigned lw = (j < 4) ? ((const unsigned*)&q0)[j] : ((const unsigned*)&q1)[j - 4];
          z0 = fmaf(val, __uint_as_float(lw << 16), z0);
          z1 = fmaf(val, __uint_as_float(lw & 0xffff0000u), z1);
          nr = fmaf(val, val, nr);
        }
      }
      z0 += __shfl_xor(z0, 32);
      z1 += __shfl_xor(z1, 32);
      nr += __shfl_xor(nr, 32);
      if (h8 == 0)
        emit_out(out, b, side ? idx_e : idx_o, sIdx - 1, z0 + lb0, z1 + lb1, nr,
                 side ? ve : vo);
    }
  }

  // ---- layer 1 ----
  f32x16 aC[2], aB[2];
  {
    float c0 = cn_b1[m31], c1 = cn_b1[32 + m31];
    float b0 = bn_b1[m31], b1v = bn_b1[32 + m31];
    #pragma unroll
    for (int r = 0; r < 16; ++r) { aC[0][r] = c0; aC[1][r] = c1; aB[0][r] = b0; aB[1][r] = b1v; }
  }
  #pragma unroll
  for (int ks = 0; ks < 8; ++ks) {
    short8 a = (ks < 4) ? aeo[ks] : aee[ks - 4];
    aC[0] = __builtin_amdgcn_mfma_f32_32x32x16_bf16(a, BFRAG(ks * 2 + 0), aC[0], 0, 0, 0);
    aC[1] = __builtin_amdgcn_mfma_f32_32x32x16_bf16(a, BFRAG(ks * 2 + 1), aC[1], 0, 0, 0);
    aB[0] = __builtin_amdgcn_mfma_f32_32x32x16_bf16(a, BFRAG(16 + ks * 2 + 0), aB[0], 0, 0, 0);
    aB[1] = __builtin_amdgcn_mfma_f32_32x32x16_bf16(a, BFRAG(16 + ks * 2 + 1), aB[1], 0, 0, 0);
  }
  #pragma unroll
  for (int ks = 8; ks < 12; ++ks) {
    short8 a = alab[ks - 8];
    aB[0] = __builtin_amdgcn_mfma_f32_32x32x16_bf16(a, BFRAG(16 + ks * 2 + 0), aB[0], 0, 0, 0);
    aB[1] = __builtin_amdgcn_mfma_f32_32x32x16_bf16(a, BFRAG(16 + ks * 2 + 1), aB[1], 0, 0, 0);
  }

  u16* hb = hbuf[wid];

  // ---- side cn: relu -> LDS transpose -> layer2 -> store e' at n=2i ----
  #pragma unroll
  for (int nt = 0; nt < 2; ++nt)
    #pragma unroll
    for (int r = 0; r < 16; ++r) {
      int row = (r & 3) + 8 * (r >> 2) + 4 * h8;
      hb[row * 72 + nt * 32 + m31] = f2bf(fmaxf(aC[nt][r], 0.f));
    }
  {
    short8 hA[4];
    #pragma unroll
    for (int f = 0; f < 4; ++f) hA[f] = *(const short8*)(hb + m31 * 72 + f * 16 + h8 * 8);
    f32x16 d[2];
    float c0 = cn_b2[m31], c1 = cn_b2[32 + m31];
    #pragma unroll
    for (int r = 0; r < 16; ++r) { d[0][r] = c0; d[1][r] = c1; }
    #pragma unroll
    for (int f = 0; f < 4; ++f) {
      d[0] = __builtin_amdgcn_mfma_f32_32x32x16_bf16(hA[f], BFRAG(40 + f * 2 + 0), d[0], 0, 0, 0);
      d[1] = __builtin_amdgcn_mfma_f32_32x32x16_bf16(hA[f], BFRAG(40 + f * 2 + 1), d[1], 0, 0, 0);
    }
    #pragma unroll
    for (int nt = 0; nt < 2; ++nt)
      #pragma unroll
      for (int r = 0; r < 16; ++r) {
        int row = (r & 3) + 8 * (r >> 2) + 4 * h8;
        int n = 2 * (i0 + row);
        e_out[(size_t)(rowb + n) * 64 + nt * 32 + m31] = f2bf(d[nt][r]);
      }
  }

  // ---- side bn: relu -> LDS transpose -> layer2 -> store e' at n=2i+1 ----
  #pragma unroll
  for (int nt = 0; nt < 2; ++nt)
    #pragma unroll
    for (int r = 0; r < 16; ++r) {
      int row = (r & 3) + 8 * (r >> 2) + 4 * h8;
      hb[row * 72 + nt * 32 + m31] = f2bf(fmaxf(aB[nt][r], 0.f));
    }
  {
    short8 hA[4];
    #pragma unroll
    for (int f = 0; f < 4; ++f) hA[f] = *(const short8*)(hb + m31 * 72 + f * 16 + h8 * 8);
    f32x16 d[2];
    float c0 = bn_b2[m31], c1 = bn_b2[32 + m31];
    #pragma unroll
    for (int r = 0; r < 16; ++r) { d[0][r] = c0; d[1][r] = c1; }
    #pragma unroll
    for (int f = 0; f < 4; ++f) {
      d[0] = __builtin_amdgcn_mfma_f32_32x32x16_bf16(hA[f], BFRAG(48 + f * 2 + 0), d[0], 0, 0, 0);
      d[1] = __builtin_amdgcn_mfma_f32_32x32x16_bf16(hA[f], BFRAG(48 + f * 2 + 1), d[1], 0, 0, 0);
    }
    #pragma unroll
    for (int nt = 0; nt < 2; ++nt)
      #pragma unroll
      for (int r = 0; r < 16; ++r) {
        int row = (r & 3) + 8 * (r >> 2) + 4 * h8;
        int n = 2 * (i0 + row) + 1;
        e_out[(size_t)(rowb + n) * 64 + nt * 32 + m31] = f2bf(d[nt][r]);
      }
  }
}

// Final epilogue (stage 10) over the last e buffer.
__global__ __launch_bounds__(256) void final_epi_kernel(
    const u16* __restrict__ e, const int* __restrict__ v,
    const float* __restrict__ llr_W, const float* __restrict__ llr_b,
    float* __restrict__ out) {
  int pos = blockIdx.x * 256 + threadIdx.x;
  int b = pos >> 10, n = pos & 1023;
  const u16* er = e + (size_t)pos * 64;
  float z0 = llr_b[0], z1 = llr_b[1], nr = 0.f;
  #pragma unroll
  for (int f = 0; f < 8; ++f) {
    uint4 q = *(const uint4*)(er + f * 8);
    #pragma unroll
    for (int j = 0; j < 8; ++j) {
      unsigned pv = ((const unsigned*)&q)[j >> 1];
      float val = __uint_as_float((j & 1) ? (pv & 0xffff0000u) : (pv << 16));
      int k = f * 8 + j;
      z0 = fmaf(val, llr_W[k * 2 + 0], z0);
      z1 = fmaf(val, llr_W[k * 2 + 1], z1);
      nr = fmaf(val, val, nr);
    }
  }
  emit_out(out, b, n, NSTAGES - 1, z0, z1, nr, v[pos] & 1);
}

extern "C" void kernel_launch(void* const* d_in, const int* in_sizes, int n_in,
                              void* d_out, int out_size, void* d_ws, size_t ws_size,
                              hipStream_t stream) {
  const int*   x      = (const int*)d_in[0];
  const float* y      = (const float*)d_in[1];
  const float* emb_W  = (const float*)d_in[2];
  const float* emb_b  = (const float*)d_in[3];
  const float* labemb = (const float*)d_in[4];
  const float* cn_W1  = (const float*)d_in[5];
  const float* cn_b1  = (const float*)d_in[6];
  const float* cn_W2  = (const float*)d_in[7];
  const float* cn_b2  = (const float*)d_in[8];
  const float* bn_W1  = (const float*)d_in[9];
  const float* bn_b1  = (const float*)d_in[10];
  const float* bn_W2  = (const float*)d_in[11];
  const float* bn_b2  = (const float*)d_in[12];
  const float* llr_W  = (const float*)d_in[13];
  const float* llr_b  = (const float*)d_in[14];
  float* out = (float*)d_out;

  char* ws = (char*)d_ws;
  size_t e_bytes = (size_t)NB * NN * 64 * sizeof(u16);     // 32 MB
  size_t v_bytes = (size_t)NB * NN * sizeof(int);          // 1 MB
  u16* e0 = (u16*)(ws);
  u16* e1 = (u16*)(ws + e_bytes);
  int* v0 = (int*)(ws + 2 * e_bytes);
  int* v1 = (int*)(ws + 2 * e_bytes + v_bytes);
  u16* wfrag = (u16*)(ws + 2 * e_bytes + 2 * v_bytes);

  prep_kernel<<<15, 256, 0, stream>>>(cn_W1, bn_W1, cn_W2, bn_W2, labemb, llr_W, wfrag);
  stage0_kernel<<<NB * NN / 256, 256, 0, stream>>>(x, y, emb_W, emb_b, llr_W, llr_b,
                                                   e0, v0, out);

  u16* ein = e0; u16* eout = e1;
  int* vin = v0; int* vout = v1;
  for (int s = 1; s <= 10; ++s) {
    stage32_kernel<<<1024, 256, 0, stream>>>(
        ein, eout, vin, vout, wfrag,
        cn_b1, bn_b1, cn_b2, bn_b2, llr_b, out, s);
    u16* te = ein; ein = eout; eout = te;
    int* tv = vin; vin = vout; vout = tv;
  }
  final_epi_kernel<<<NB * NN / 256, 256, 0, stream>>>(ein, vin, llr_W, llr_b, out);
}

// Round 4
// 372.486 us; speedup vs baseline: 5.3629x; 1.0201x over previous
//
#include <hip/hip_runtime.h>
#include <hip/hip_bf16.h>

#define NB 256
#define NN 1024
#define NSTAGES 11
#define EPSF 1e-7f

typedef unsigned short u16;
typedef __attribute__((ext_vector_type(8))) short short8;
typedef __attribute__((ext_vector_type(16))) float f32x16;

// Output layout (float32, concatenated):
//   losses (B, 11, N); preds (B, N, 11, 2); norms (B, 11, N)
static constexpr size_t PRED_BASE = (size_t)NB * NSTAGES * NN;
static constexpr size_t NORM_BASE = PRED_BASE + (size_t)NB * NN * NSTAGES * 2;

// wfrag layout (u16 units), B-fragments for mfma_f32_32x32x16_bf16 with
// channel-pair permutation: value B[k][n] held by lane l, frag (ks,nt):
//   n = 2*(l&31) + nt,  k = ks*16 + (l>>5)*8 + j.
//   cn_W1: fi = ks*2+nt        (0..15)   K=128
//   bn_W1: fi = 16 + ks*2+nt   (16..39)  K=192
//   cn_W2: fi = 40 + ks*2+nt   (40..47)  K=64
//   bn_W2: fi = 48 + ks*2+nt   (48..55)  K=64
//   llr_W packed bf16 pairs (u32[64], natural order) at u16 offset 28672
//   lab_emb bf16 (2x64, natural order)               at u16 offset 28800
static constexpr int LW_OFF  = 28672;
static constexpr int LAB_OFF = 28800;
static constexpr int LDS_FRAGS = 21;   // frags 0..20 in LDS; LDS stays <40KB for 4 blocks/CU

__device__ __forceinline__ u16 f2bf(float f) {
  unsigned u = __float_as_uint(f);
  unsigned r = (u + 0x7fffu + ((u >> 16) & 1u)) >> 16;
  return (u16)r;
}

__device__ __forceinline__ unsigned pack_bf2(float a, float b) {
  __hip_bfloat162 h = __float22bfloat162_rn(make_float2(a, b));
  return *(unsigned*)&h;
}

__device__ __forceinline__ void emit_out(float* __restrict__ out, int b, int n, int s,
                                         float z0, float z1, float nrm2, int label) {
  float m  = fmaxf(z0, z1);
  float p0 = expf(z0 - m), p1 = expf(z1 - m);
  float inv = 1.0f / (p0 + p1);
  p0 *= inv; p1 *= inv;
  float pt = label ? p1 : p0;
  pt = fminf(fmaxf(pt, EPSF), 1.0f);
  out[((size_t)b * NSTAGES + s) * NN + n] = -logf(pt);
  size_t pb = PRED_BASE + (((size_t)b * NN + n) * NSTAGES + s) * 2;
  out[pb + 0] = p0;
  out[pb + 1] = p1;
  out[NORM_BASE + ((size_t)b * NSTAGES + s) * NN + n] = sqrtf(nrm2);
}

__global__ __launch_bounds__(256) void prep_kernel(
    const float* __restrict__ cn_W1, const float* __restrict__ bn_W1,
    const float* __restrict__ cn_W2, const float* __restrict__ bn_W2,
    const float* __restrict__ lab_emb, const float* __restrict__ llr_W,
    u16* __restrict__ wfrag) {
  int t = blockIdx.x * 256 + threadIdx.x;
  if (t < 3584) {
    int f = t >> 6, l = t & 63, h = l >> 5, c = l & 31;
    const float* src; int ks, nt;
    if (f < 16)      { src = cn_W1; ks = f >> 1; nt = f & 1; }
    else if (f < 40) { int g = f - 16; src = bn_W1; ks = g >> 1; nt = g & 1; }
    else if (f < 48) { int g = f - 40; src = cn_W2; ks = g >> 1; nt = g & 1; }
    else             { int g = f - 48; src = bn_W2; ks = g >> 1; nt = g & 1; }
    int col = 2 * c + nt;                       // channel-pair permutation
    u16 vals[8];
    #pragma unroll
    for (int j = 0; j < 8; ++j) {
      int k = ks * 16 + h * 8 + j;
      vals[j] = f2bf(src[k * 64 + col]);
    }
    uint4 u;
    u.x = (unsigned)vals[0] | ((unsigned)vals[1] << 16);
    u.y = (unsigned)vals[2] | ((unsigned)vals[3] << 16);
    u.z = (unsigned)vals[4] | ((unsigned)vals[5] << 16);
    u.w = (unsigned)vals[6] | ((unsigned)vals[7] << 16);
    *(uint4*)(wfrag + (size_t)t * 8) = u;
  } else if (t < 3648) {
    int k = t - 3584;
    unsigned w = (unsigned)f2bf(llr_W[k * 2]) | ((unsigned)f2bf(llr_W[k * 2 + 1]) << 16);
    ((unsigned*)(wfrag + LW_OFF))[k] = w;
  } else if (t < 3776) {
    int i = t - 3648;
    wfrag[LAB_OFF + i] = f2bf(lab_emb[i]);
  }
}

// Stage 0: e = y @ emb_W + emb_b (K=2, vector path); store e as bf16; emit s=0.
__global__ __launch_bounds__(256) void stage0_kernel(
    const int* __restrict__ x, const float* __restrict__ y,
    const float* __restrict__ emb_W, const float* __restrict__ emb_b,
    const float* __restrict__ llr_W, const float* __restrict__ llr_b,
    u16* __restrict__ e_out, int* __restrict__ v_out, float* __restrict__ out) {
  int pos = blockIdx.x * 256 + threadIdx.x;     // [0, B*N)
  int b = pos >> 10, n = pos & (NN - 1);
  float y0 = y[(size_t)pos * 2 + 0];
  float y1 = y[(size_t)pos * 2 + 1];
  float z0 = llr_b[0], z1 = llr_b[1], nrm = 0.0f;
  u16* erow = e_out + (size_t)pos * 64;
  for (int o8 = 0; o8 < 8; ++o8) {
    unsigned vals[4];
    #pragma unroll
    for (int jj = 0; jj < 4; ++jj) {
      int o = o8 * 8 + jj * 2;
      float e0 = fmaf(y0, emb_W[o],     fmaf(y1, emb_W[64 + o],     emb_b[o]));
      float e1 = fmaf(y0, emb_W[o + 1], fmaf(y1, emb_W[64 + o + 1], emb_b[o + 1]));
      vals[jj] = pack_bf2(e0, e1);
      z0 = fmaf(e0, llr_W[o * 2 + 0], z0);
      z1 = fmaf(e0, llr_W[o * 2 + 1], z1);
      nrm = fmaf(e0, e0, nrm);
      z0 = fmaf(e1, llr_W[o * 2 + 2], z0);
      z1 = fmaf(e1, llr_W[o * 2 + 3], z1);
      nrm = fmaf(e1, e1, nrm);
    }
    uint4 u; u.x = vals[0]; u.y = vals[1]; u.z = vals[2]; u.w = vals[3];
    *(uint4*)(erow + o8 * 8) = u;
  }
  int v = x[pos] & 1;
  v_out[pos] = v;
  emit_out(out, b, n, 0, z0, z1, nrm, v);
}

// B-fragment fetch: compile-time id -> LDS or global (folds after unroll).
#define BFRAG(FI) (((FI) < LDS_FRAGS) ? *(const short8*)(wlds + (FI) * 512 + ln * 8) \
                                      : *(const short8*)(wfrag + (size_t)(FI) * 512 + ln * 8))

// One polar stage. 256 threads = 4 waves; each wave = one 32-pair tile via
// mfma_f32_32x32x16_bf16.  A: m=lane&31, k=(lane>>5)*8+j;
// C/D: col(lane,nt) = 2*(lane&31)+nt (permuted), row=(r&3)+8*(r>>2)+4*(lane>>5).
// Stage sIdx-1's loss/pred/norm epilogue is piggybacked on the input rows.
__global__ __launch_bounds__(256, 4) void stage32_kernel(
    const u16* __restrict__ e_in, u16* __restrict__ e_out,
    const int* __restrict__ v_in, int* __restrict__ v_out,
    const u16* __restrict__ wfrag,
    const float* __restrict__ cn_b1, const float* __restrict__ bn_b1,
    const float* __restrict__ cn_b2, const float* __restrict__ bn_b2,
    const float* __restrict__ llr_b,
    float* __restrict__ out, int sIdx) {
  __shared__ __align__(16) u16 wlds[LDS_FRAGS * 512];
  __shared__ __align__(16) u16 hbuf[4][32 * 72];
  int tid = threadIdx.x;
  {
    const uint4* src = (const uint4*)wfrag;
    uint4* dst = (uint4*)wlds;
    for (int i = tid; i < LDS_FRAGS * 64; i += 256) dst[i] = src[i];
  }
  __syncthreads();

  int ln = tid & 63, wid = tid >> 6;
  int m31 = ln & 31, h8 = ln >> 5;
  int tile = blockIdx.x * 4 + wid;      // [0, 4096)
  int P0 = tile << 5;                   // base pair index
  int b = P0 >> 9, i0 = P0 & 511;
  int rowb = b << 10;
  int log_half = sIdx - 1, half = 1 << log_half;

  int im = i0 + m31;
  int g = im >> log_half, u = im & (half - 1);
  int idx_o = g * (half << 1) + u, idx_e = idx_o + half;
  const u16* eo = e_in + (size_t)(rowb + idx_o) * 64;
  const u16* ee = e_in + (size_t)(rowb + idx_e) * 64;
  int vo = v_in[rowb + idx_o] & 1;
  int ve = v_in[rowb + idx_e] & 1;
  int vx = vo ^ ve;

  short8 aeo[4], aee[4], alab[4];
  #pragma unroll
  for (int f = 0; f < 4; ++f) {
    aeo[f] = *(const short8*)(eo + f * 16 + h8 * 8);
    aee[f] = *(const short8*)(ee + f * 16 + h8 * 8);
  }
  const u16* labT = wfrag + LAB_OFF + vx * 64;
  #pragma unroll
  for (int f = 0; f < 4; ++f) alab[f] = *(const short8*)(labT + f * 16 + h8 * 8);

  if (h8 == 0) {
    *(int2*)(v_out + rowb + 2 * im) = make_int2(vx, ve);
  }

  // ---- piggybacked epilogue for stage sIdx-1 on the input rows ----
  if (sIdx >= 2) {
    const unsigned* lwp = (const unsigned*)(wfrag + LW_OFF);
    float lb0 = llr_b[0], lb1 = llr_b[1];
    #pragma unroll
    for (int side = 0; side < 2; ++side) {
      float z0 = 0.f, z1 = 0.f, nr = 0.f;
      #pragma unroll
      for (int f = 0; f < 4; ++f) {
        short8 av8 = side ? aee[f] : aeo[f];
        uint4 q0 = *(const uint4*)(lwp + f * 16 + h8 * 8);
        uint4 q1 = *(const uint4*)(lwp + f * 16 + h8 * 8 + 4);
        #pragma unroll
        for (int j = 0; j < 8; ++j) {
          unsigned pv = ((const unsigned*)&av8)[j >> 1];
          float val = __uint_as_float((j & 1) ? (pv & 0xffff0000u) : (pv << 16));
          unsigned lw = (j < 4) ? ((const unsigned*)&q0)[j] : ((const unsigned*)&q1)[j - 4];
          z0 = fmaf(val, __uint_as_float(lw << 16), z0);
          z1 = fmaf(val, __uint_as_float(lw & 0xffff0000u), z1);
          nr = fmaf(val, val, nr);
        }
      }
      z0 += __shfl_xor(z0, 32);
      z1 += __shfl_xor(z1, 32);
      nr += __shfl_xor(nr, 32);
      if (h8 == 0)
        emit_out(out, b, side ? idx_e : idx_o, sIdx - 1, z0 + lb0, z1 + lb1, nr,
                 side ? ve : vo);
    }
  }

  // ---- layer 1 ----
  f32x16 aC[2], aB[2];
  {
    float2 c = *(const float2*)(cn_b1 + 2 * m31);
    float2 bv = *(const float2*)(bn_b1 + 2 * m31);
    #pragma unroll
    for (int r = 0; r < 16; ++r) { aC[0][r] = c.x; aC[1][r] = c.y; aB[0][r] = bv.x; aB[1][r] = bv.y; }
  }
  #pragma unroll
  for (int ks = 0; ks < 8; ++ks) {
    short8 a = (ks < 4) ? aeo[ks] : aee[ks - 4];
    aC[0] = __builtin_amdgcn_mfma_f32_32x32x16_bf16(a, BFRAG(ks * 2 + 0), aC[0], 0, 0, 0);
    aC[1] = __builtin_amdgcn_mfma_f32_32x32x16_bf16(a, BFRAG(ks * 2 + 1), aC[1], 0, 0, 0);
    aB[0] = __builtin_amdgcn_mfma_f32_32x32x16_bf16(a, BFRAG(16 + ks * 2 + 0), aB[0], 0, 0, 0);
    aB[1] = __builtin_amdgcn_mfma_f32_32x32x16_bf16(a, BFRAG(16 + ks * 2 + 1), aB[1], 0, 0, 0);
  }
  #pragma unroll
  for (int ks = 8; ks < 12; ++ks) {
    short8 a = alab[ks - 8];
    aB[0] = __builtin_amdgcn_mfma_f32_32x32x16_bf16(a, BFRAG(16 + ks * 2 + 0), aB[0], 0, 0, 0);
    aB[1] = __builtin_amdgcn_mfma_f32_32x32x16_bf16(a, BFRAG(16 + ks * 2 + 1), aB[1], 0, 0, 0);
  }

  u16* hb = hbuf[wid];

  // ---- side cn: relu -> LDS transpose (packed b32) -> layer2 -> e' at n=2i ----
  #pragma unroll
  for (int r = 0; r < 16; ++r) {
    int row = (r & 3) + 8 * (r >> 2) + 4 * h8;
    *(unsigned*)(hb + row * 72 + 2 * m31) = pack_bf2(fmaxf(aC[0][r], 0.f), fmaxf(aC[1][r], 0.f));
  }
  {
    short8 hA[4];
    #pragma unroll
    for (int f = 0; f < 4; ++f) hA[f] = *(const short8*)(hb + m31 * 72 + f * 16 + h8 * 8);
    f32x16 d[2];
    float2 c = *(const float2*)(cn_b2 + 2 * m31);
    #pragma unroll
    for (int r = 0; r < 16; ++r) { d[0][r] = c.x; d[1][r] = c.y; }
    #pragma unroll
    for (int f = 0; f < 4; ++f) {
      d[0] = __builtin_amdgcn_mfma_f32_32x32x16_bf16(hA[f], BFRAG(40 + f * 2 + 0), d[0], 0, 0, 0);
      d[1] = __builtin_amdgcn_mfma_f32_32x32x16_bf16(hA[f], BFRAG(40 + f * 2 + 1), d[1], 0, 0, 0);
    }
    #pragma unroll
    for (int r = 0; r < 16; ++r) {
      int row = (r & 3) + 8 * (r >> 2) + 4 * h8;
      int n = 2 * (i0 + row);
      ((unsigned*)e_out)[(size_t)(rowb + n) * 32 + m31] = pack_bf2(d[0][r], d[1][r]);
    }
  }

  // ---- side bn: relu -> LDS transpose -> layer2 -> e' at n=2i+1 ----
  #pragma unroll
  for (int r = 0; r < 16; ++r) {
    int row = (r & 3) + 8 * (r >> 2) + 4 * h8;
    *(unsigned*)(hb + row * 72 + 2 * m31) = pack_bf2(fmaxf(aB[0][r], 0.f), fmaxf(aB[1][r], 0.f));
  }
  {
    short8 hA[4];
    #pragma unroll
    for (int f = 0; f < 4; ++f) hA[f] = *(const short8*)(hb + m31 * 72 + f * 16 + h8 * 8);
    f32x16 d[2];
    float2 c = *(const float2*)(bn_b2 + 2 * m31);
    #pragma unroll
    for (int r = 0; r < 16; ++r) { d[0][r] = c.x; d[1][r] = c.y; }
    #pragma unroll
    for (int f = 0; f < 4; ++f) {
      d[0] = __builtin_amdgcn_mfma_f32_32x32x16_bf16(hA[f], BFRAG(48 + f * 2 + 0), d[0], 0, 0, 0);
      d[1] = __builtin_amdgcn_mfma_f32_32x32x16_bf16(hA[f], BFRAG(48 + f * 2 + 1), d[1], 0, 0, 0);
    }
    #pragma unroll
    for (int r = 0; r < 16; ++r) {
      int row = (r & 3) + 8 * (r >> 2) + 4 * h8;
      int n = 2 * (i0 + row) + 1;
      ((unsigned*)e_out)[(size_t)(rowb + n) * 32 + m31] = pack_bf2(d[0][r], d[1][r]);
    }
  }
}

// Final epilogue (stage 10) over the last e buffer.
__global__ __launch_bounds__(256) void final_epi_kernel(
    const u16* __restrict__ e, const int* __restrict__ v,
    const float* __restrict__ llr_W, const float* __restrict__ llr_b,
    float* __restrict__ out) {
  int pos = blockIdx.x * 256 + threadIdx.x;
  int b = pos >> 10, n = pos & 1023;
  const u16* er = e + (size_t)pos * 64;
  float z0 = llr_b[0], z1 = llr_b[1], nr = 0.f;
  #pragma unroll
  for (int f = 0; f < 8; ++f) {
    uint4 q = *(const uint4*)(er + f * 8);
    #pragma unroll
    for (int j = 0; j < 8; ++j) {
      unsigned pv = ((const unsigned*)&q)[j >> 1];
      float val = __uint_as_float((j & 1) ? (pv & 0xffff0000u) : (pv << 16));
      int k = f * 8 + j;
      z0 = fmaf(val, llr_W[k * 2 + 0], z0);
      z1 = fmaf(val, llr_W[k * 2 + 1], z1);
      nr = fmaf(val, val, nr);
    }
  }
  emit_out(out, b, n, NSTAGES - 1, z0, z1, nr, v[pos] & 1);
}

extern "C" void kernel_launch(void* const* d_in, const int* in_sizes, int n_in,
                              void* d_out, int out_size, void* d_ws, size_t ws_size,
                              hipStream_t stream) {
  const int*   x      = (const int*)d_in[0];
  const float* y      = (const float*)d_in[1];
  const float* emb_W  = (const float*)d_in[2];
  const float* emb_b  = (const float*)d_in[3];
  const float* labemb = (const float*)d_in[4];
  const float* cn_W1  = (const float*)d_in[5];
  const float* cn_b1  = (const float*)d_in[6];
  const float* cn_W2  = (const float*)d_in[7];
  const float* cn_b2  = (const float*)d_in[8];
  const float* bn_W1  = (const float*)d_in[9];
  const float* bn_b1  = (const float*)d_in[10];
  const float* bn_W2  = (const float*)d_in[11];
  const float* bn_b2  = (const float*)d_in[12];
  const float* llr_W  = (const float*)d_in[13];
  const float* llr_b  = (const float*)d_in[14];
  float* out = (float*)d_out;

  char* ws = (char*)d_ws;
  size_t e_bytes = (size_t)NB * NN * 64 * sizeof(u16);     // 32 MB
  size_t v_bytes = (size_t)NB * NN * sizeof(int);          // 1 MB
  u16* e0 = (u16*)(ws);
  u16* e1 = (u16*)(ws + e_bytes);
  int* v0 = (int*)(ws + 2 * e_bytes);
  int* v1 = (int*)(ws + 2 * e_bytes + v_bytes);
  u16* wfrag = (u16*)(ws + 2 * e_bytes + 2 * v_bytes);

  prep_kernel<<<15, 256, 0, stream>>>(cn_W1, bn_W1, cn_W2, bn_W2, labemb, llr_W, wfrag);
  stage0_kernel<<<NB * NN / 256, 256, 0, stream>>>(x, y, emb_W, emb_b, llr_W, llr_b,
                                                   e0, v0, out);

  u16* ein = e0; u16* eout = e1;
  int* vin = v0; int* vout = v1;
  for (int s = 1; s <= 10; ++s) {
    stage32_kernel<<<1024, 256, 0, stream>>>(
        ein, eout, vin, vout, wfrag,
        cn_b1, bn_b1, cn_b2, bn_b2, llr_b, out, s);
    u16* te = ein; ein = eout; eout = te;
    int* tv = vin; vin = vout; vout = tv;
  }
  final_epi_kernel<<<NB * NN / 256, 256, 0, stream>>>(ein, vin, llr_W, llr_b, out);
}

// Round 5
// 278.381 us; speedup vs baseline: 7.1758x; 1.3380x over previous
//
#include <hip/hip_runtime.h>
#include <hip/hip_bf16.h>

#define NB 256
#define NN 1024
#define NSTAGES 11
#define EPSF 1e-7f

typedef unsigned short u16;
typedef unsigned int u32;
typedef unsigned long long u64;
typedef __attribute__((ext_vector_type(8))) short short8;
typedef __attribute__((ext_vector_type(16))) float f32x16;

// Output layout (float32, concatenated):
//   losses (B, 11, N); preds (B, N, 11, 2); norms (B, 11, N)
static constexpr size_t PRED_BASE = (size_t)NB * NSTAGES * NN;
static constexpr size_t NORM_BASE = PRED_BASE + (size_t)NB * NN * NSTAGES * 2;

// wfrag (u16 units): 48 B-fragments for mfma_f32_32x32x16_bf16, channel-pair
// permuted: B[k][n] at lane l, frag (ks,nt): n = 2*(l&31)+nt, k = ks*16+(l>>5)*8+j.
//   cn_W1: 0..15 (K=128) | bn_W1[0:128]: 16..31 | cn_W2: 32..39 | bn_W2: 40..47
//   packed llr_W bf16 pairs (u32[64]) at u16 offset 24576
// labW_g (separate fp32[2][64]): lab_emb[v] @ bn_W1[128:192] + bn_b1  (prep-fused)
static constexpr int LW_OFF = 24576;

__device__ __forceinline__ u16 f2bf(float f) {
  unsigned u = __float_as_uint(f);
  unsigned r = (u + 0x7fffu + ((u >> 16) & 1u)) >> 16;
  return (u16)r;
}
__device__ __forceinline__ unsigned pack_bf2(float a, float b) {
  __hip_bfloat162 h = __float22bfloat162_rn(make_float2(a, b));
  return *(unsigned*)&h;
}
__device__ __forceinline__ u32 spread16(u32 v) {
  v = (v | (v << 8)) & 0x00FF00FFu;
  v = (v | (v << 4)) & 0x0F0F0F0Fu;
  v = (v | (v << 2)) & 0x33333333u;
  v = (v | (v << 1)) & 0x55555555u;
  return v;
}
__device__ __forceinline__ void emit_out(float* __restrict__ out, int b, int n, int s,
                                         float z0, float z1, float nrm2, int label) {
  float m  = fmaxf(z0, z1);
  float p0 = expf(z0 - m), p1 = expf(z1 - m);
  float inv = 1.0f / (p0 + p1);
  p0 *= inv; p1 *= inv;
  float pt = label ? p1 : p0;
  pt = fminf(fmaxf(pt, EPSF), 1.0f);
  out[((size_t)b * NSTAGES + s) * NN + n] = -logf(pt);
  size_t pb = PRED_BASE + (((size_t)b * NN + n) * NSTAGES + s) * 2;
  out[pb + 0] = p0;
  out[pb + 1] = p1;
  out[NORM_BASE + ((size_t)b * NSTAGES + s) * NN + n] = sqrtf(nrm2);
}

// Swizzled e-LDS addressing (u16 units). Row = 64 u16 (128 B) = 8 chunks of
// 16 B; physical chunk = logical_chunk XOR (row & 7) to break stride-128 bank
// conflicts on per-lane row gathers.
__device__ __forceinline__ int eaddr(int row, int c16) {
  return row * 64 + (((c16) ^ (row & 7)) << 3);
}
__device__ __forceinline__ int eaddr32(int row, int m31) {
  return row * 64 + (((((m31) >> 2) ^ (row & 7)) << 3) | (((m31) & 3) << 1));
}

__global__ __launch_bounds__(256) void prep_kernel(
    const float* __restrict__ cn_W1, const float* __restrict__ bn_W1,
    const float* __restrict__ cn_W2, const float* __restrict__ bn_W2,
    const float* __restrict__ lab_emb, const float* __restrict__ llr_W,
    const float* __restrict__ bn_b1,
    u16* __restrict__ wfrag, float* __restrict__ labW_g) {
  int t = blockIdx.x * 256 + threadIdx.x;
  if (t < 3072) {
    int f = t >> 6, l = t & 63, h = l >> 5, c = l & 31;
    const float* src; int ks, nt;
    if (f < 16)      { src = cn_W1; ks = f >> 1; nt = f & 1; }
    else if (f < 32) { int g = f - 16; src = bn_W1; ks = g >> 1; nt = g & 1; }
    else if (f < 40) { int g = f - 32; src = cn_W2; ks = g >> 1; nt = g & 1; }
    else             { int g = f - 40; src = bn_W2; ks = g >> 1; nt = g & 1; }
    int col = 2 * c + nt;
    u16 vals[8];
    #pragma unroll
    for (int j = 0; j < 8; ++j) {
      int k = ks * 16 + h * 8 + j;
      vals[j] = f2bf(src[k * 64 + col]);
    }
    uint4 u;
    u.x = (unsigned)vals[0] | ((unsigned)vals[1] << 16);
    u.y = (unsigned)vals[2] | ((unsigned)vals[3] << 16);
    u.z = (unsigned)vals[4] | ((unsigned)vals[5] << 16);
    u.w = (unsigned)vals[6] | ((unsigned)vals[7] << 16);
    *(uint4*)(wfrag + (size_t)t * 8) = u;
  } else if (t < 3136) {
    int k = t - 3072;
    unsigned wv = (unsigned)f2bf(llr_W[k * 2]) | ((unsigned)f2bf(llr_W[k * 2 + 1]) << 16);
    ((unsigned*)(wfrag + LW_OFF))[k] = wv;
  } else if (t < 3264) {
    int idx = t - 3136;
    int v = idx >> 6, c = idx & 63;
    float acc = bn_b1[c];
    for (int d = 0; d < 64; ++d)
      acc = fmaf(lab_emb[v * 64 + d], bn_W1[(128 + d) * 64 + c], acc);
    labW_g[idx] = acc;
  }
}

#define BFR(FI) (((FI) < 28) ? *(const short8*)(wlds + (FI) * 512 + ln * 8) \
                             : *(const short8*)(wfrag + (FI) * 512 + ln * 8))

// Persistent kernel: 1 block per batch row b, e-row (1024x64 bf16 = 128 KB)
// resident in LDS across all 10 stages. 512 threads = 8 waves; wave w owns
// pairs [64w, 64w+64) as 2 tiles of 32 (mfma_f32_32x32x16_bf16).
// Per stage: read A-frags (all input rows) -> barrier -> layer1 -> H into own
// output rows (in-place) -> layer2 -> e' overwrites H -> barrier.
__global__ __launch_bounds__(512) void polar_kernel(
    const int* __restrict__ x, const float* __restrict__ y,
    const float* __restrict__ emb_W, const float* __restrict__ emb_b,
    const u16* __restrict__ wfrag, const float* __restrict__ labW_g,
    const float* __restrict__ cn_b1, const float* __restrict__ cn_b2,
    const float* __restrict__ bn_b2, const float* __restrict__ llr_W,
    const float* __restrict__ llr_b, float* __restrict__ out) {
  __shared__ __align__(16) u16 eL[NN * 64];        // 131072 B
  __shared__ __align__(16) u16 wlds[28 * 512];     // 28672 B
  __shared__ u32 vmask[2][32];                     // 256 B
  __shared__ float labW[2][64];                    // 512 B

  const int tid = threadIdx.x;
  const int w = tid >> 6, ln = tid & 63;
  const int m31 = ln & 31, h8 = ln >> 5;
  const int b = blockIdx.x;

  for (int i = tid; i < 28 * 64; i += 512)
    ((uint4*)wlds)[i] = ((const uint4*)wfrag)[i];
  if (tid < 128) ((float*)labW)[tid] = labW_g[tid];

  const float lb0 = llr_b[0], lb1 = llr_b[1];
  const float2 cb1 = *(const float2*)(cn_b1 + 2 * m31);
  const float2 cb2 = *(const float2*)(cn_b2 + 2 * m31);
  const float2 bb2 = *(const float2*)(bn_b2 + 2 * m31);

  // ---------------- stage 0: e = y @ emb_W + emb_b ----------------
  #pragma unroll
  for (int rep = 0; rep < 2; ++rep) {
    int n = rep * 512 + tid;
    float2 yv = *(const float2*)(y + ((size_t)b * NN + n) * 2);
    float z0 = lb0, z1 = lb1, nr = 0.f;
    #pragma unroll
    for (int o8 = 0; o8 < 8; ++o8) {
      u32 vals[4];
      #pragma unroll
      for (int jj = 0; jj < 4; ++jj) {
        int o = o8 * 8 + jj * 2;
        float e0 = fmaf(yv.x, emb_W[o],     fmaf(yv.y, emb_W[64 + o],     emb_b[o]));
        float e1 = fmaf(yv.x, emb_W[o + 1], fmaf(yv.y, emb_W[64 + o + 1], emb_b[o + 1]));
        vals[jj] = pack_bf2(e0, e1);
        z0 = fmaf(e0, llr_W[o * 2 + 0], z0); z1 = fmaf(e0, llr_W[o * 2 + 1], z1);
        nr = fmaf(e0, e0, nr);
        z0 = fmaf(e1, llr_W[o * 2 + 2], z0); z1 = fmaf(e1, llr_W[o * 2 + 3], z1);
        nr = fmaf(e1, e1, nr);
      }
      uint4 q; q.x = vals[0]; q.y = vals[1]; q.z = vals[2]; q.w = vals[3];
      *(uint4*)(eL + eaddr(n, o8)) = q;
    }
    int v = x[(size_t)b * NN + n] & 1;
    emit_out(out, b, n, 0, z0, z1, nr, v);
    u64 bm = __ballot(v != 0);
    if (ln == 0)  vmask[0][rep * 16 + 2 * w]     = (u32)bm;
    if (ln == 32) vmask[0][rep * 16 + 2 * w + 1] = (u32)(bm >> 32);
  }
  __syncthreads();

  const float2 lwv0 = *(const float2*)(&labW[0][2 * m31]);
  const float2 lwv1 = *(const float2*)(&labW[1][2 * m31]);

  // ---------------- stages 1..10 ----------------
  #pragma unroll 1
  for (int s = 1; s <= 10; ++s) {
    const int sh = s - 1;
    const int half = 1 << sh;
    const u32* vmR = vmask[(s - 1) & 1];
    u32* vmW = vmask[s & 1];

    short8 Ao[2][4], Ae[2][4];
    int io[2], ie[2], vo[2], ve[2], vx[2];
    u32 bxs[2];
    #pragma unroll
    for (int t = 0; t < 2; ++t) {
      int i = 64 * w + 32 * t + m31;
      int g = i >> sh, u = i & (half - 1);
      io[t] = g * (half << 1) + u;
      ie[t] = io[t] + half;
      #pragma unroll
      for (int f = 0; f < 4; ++f) {
        Ao[t][f] = *(const short8*)(eL + eaddr(io[t], f * 2 + h8));
        Ae[t][f] = *(const short8*)(eL + eaddr(ie[t], f * 2 + h8));
      }
      vo[t] = (vmR[io[t] >> 5] >> (io[t] & 31)) & 1;
      ve[t] = (vmR[ie[t] >> 5] >> (ie[t] & 31)) & 1;
      vx[t] = vo[t] ^ ve[t];
      u32 bx = (u32)__ballot(vx[t] != 0);
      u32 be = (u32)__ballot(ve[t] != 0);
      bxs[t] = bx;
      u32 lo = spread16(bx & 0xffffu) | (spread16(be & 0xffffu) << 1);
      u32 hi = spread16(bx >> 16) | (spread16(be >> 16) << 1);
      if (ln == 0) { vmW[4 * w + 2 * t] = lo; vmW[4 * w + 2 * t + 1] = hi; }
    }
    __syncthreads();   // all e reads done; output rows now writable

    // piggybacked loss/pred/norm epilogue for stage s-1 (uses A-frags in regs)
    if (s >= 2) {
      const uint4* lwq = (const uint4*)(wfrag + LW_OFF);
      uint4 lq[4][2];
      #pragma unroll
      for (int f = 0; f < 4; ++f) {
        lq[f][0] = lwq[f * 4 + h8 * 2];
        lq[f][1] = lwq[f * 4 + h8 * 2 + 1];
      }
      #pragma unroll
      for (int t = 0; t < 2; ++t) {
        #pragma unroll
        for (int side = 0; side < 2; ++side) {
          float z0 = 0.f, z1 = 0.f, nr = 0.f;
          #pragma unroll
          for (int f = 0; f < 4; ++f) {
            short8 av8 = side ? Ae[t][f] : Ao[t][f];
            #pragma unroll
            for (int j = 0; j < 8; ++j) {
              u32 pv = ((const u32*)&av8)[j >> 1];
              float val = __uint_as_float((j & 1) ? (pv & 0xffff0000u) : (pv << 16));
              u32 lwp = (j < 4) ? ((const u32*)&lq[f][0])[j] : ((const u32*)&lq[f][1])[j - 4];
              z0 = fmaf(val, __uint_as_float(lwp << 16), z0);
              z1 = fmaf(val, __uint_as_float(lwp & 0xffff0000u), z1);
              nr = fmaf(val, val, nr);
            }
          }
          z0 += __shfl_xor(z0, 32);
          z1 += __shfl_xor(z1, 32);
          nr += __shfl_xor(nr, 32);
          if (h8 == 0)
            emit_out(out, b, side ? ie[t] : io[t], s - 1,
                     z0 + lb0, z1 + lb1, nr, side ? ve[t] : vo[t]);
        }
      }
    }

    // ---- layer-1 cn (K=128) ----
    f32x16 a0[2], a1[2];
    #pragma unroll
    for (int t = 0; t < 2; ++t)
      #pragma unroll
      for (int r = 0; r < 16; ++r) { a0[t][r] = cb1.x; a1[t][r] = cb1.y; }
    #pragma unroll
    for (int ks = 0; ks < 8; ++ks) {
      short8 B0 = BFR(ks * 2 + 0);
      short8 B1 = BFR(ks * 2 + 1);
      #pragma unroll
      for (int t = 0; t < 2; ++t) {
        short8 a = (ks < 4) ? Ao[t][ks] : Ae[t][ks - 4];
        a0[t] = __builtin_amdgcn_mfma_f32_32x32x16_bf16(a, B0, a0[t], 0, 0, 0);
        a1[t] = __builtin_amdgcn_mfma_f32_32x32x16_bf16(a, B1, a1[t], 0, 0, 0);
      }
    }
    #pragma unroll
    for (int t = 0; t < 2; ++t) {
      int obase = 128 * w + 64 * t;
      #pragma unroll
      for (int r = 0; r < 16; ++r) {
        int row = (r & 3) + 8 * (r >> 2) + 4 * h8;
        int R = obase + 2 * row;                 // H_cn at even rows
        *(u32*)(eL + eaddr32(R, m31)) =
            pack_bf2(fmaxf(a0[t][r], 0.f), fmaxf(a1[t][r], 0.f));
      }
    }

    // ---- layer-1 bn (K=128 + fused labW bias) ----
    #pragma unroll
    for (int t = 0; t < 2; ++t)
      #pragma unroll
      for (int r = 0; r < 16; ++r) {
        int row = (r & 3) + 8 * (r >> 2) + 4 * h8;
        int bit = (bxs[t] >> row) & 1;
        a0[t][r] = bit ? lwv1.x : lwv0.x;
        a1[t][r] = bit ? lwv1.y : lwv0.y;
      }
    #pragma unroll
    for (int ks = 0; ks < 8; ++ks) {
      short8 B0 = BFR(16 + ks * 2 + 0);
      short8 B1 = BFR(16 + ks * 2 + 1);
      #pragma unroll
      for (int t = 0; t < 2; ++t) {
        short8 a = (ks < 4) ? Ao[t][ks] : Ae[t][ks - 4];
        a0[t] = __builtin_amdgcn_mfma_f32_32x32x16_bf16(a, B0, a0[t], 0, 0, 0);
        a1[t] = __builtin_amdgcn_mfma_f32_32x32x16_bf16(a, B1, a1[t], 0, 0, 0);
      }
    }
    #pragma unroll
    for (int t = 0; t < 2; ++t) {
      int obase = 128 * w + 64 * t;
      #pragma unroll
      for (int r = 0; r < 16; ++r) {
        int row = (r & 3) + 8 * (r >> 2) + 4 * h8;
        int R = obase + 2 * row + 1;             // H_bn at odd rows
        *(u32*)(eL + eaddr32(R, m31)) =
            pack_bf2(fmaxf(a0[t][r], 0.f), fmaxf(a1[t][r], 0.f));
      }
    }

    // ---- layer-2 cn ----
    {
      short8 Hc[2][4];
      #pragma unroll
      for (int t = 0; t < 2; ++t) {
        int R = 128 * w + 64 * t + 2 * m31;
        #pragma unroll
        for (int f = 0; f < 4; ++f)
          Hc[t][f] = *(const short8*)(eL + eaddr(R, f * 2 + h8));
      }
      f32x16 d0[2], d1[2];
      #pragma unroll
      for (int t = 0; t < 2; ++t)
        #pragma unroll
        for (int r = 0; r < 16; ++r) { d0[t][r] = cb2.x; d1[t][r] = cb2.y; }
      #pragma unroll
      for (int ks = 0; ks < 4; ++ks) {
        short8 B0 = BFR(32 + ks * 2 + 0);
        short8 B1 = BFR(32 + ks * 2 + 1);
        #pragma unroll
        for (int t = 0; t < 2; ++t) {
          d0[t] = __builtin_amdgcn_mfma_f32_32x32x16_bf16(Hc[t][ks], B0, d0[t], 0, 0, 0);
          d1[t] = __builtin_amdgcn_mfma_f32_32x32x16_bf16(Hc[t][ks], B1, d1[t], 0, 0, 0);
        }
      }
      #pragma unroll
      for (int t = 0; t < 2; ++t) {
        int obase = 128 * w + 64 * t;
        #pragma unroll
        for (int r = 0; r < 16; ++r) {
          int row = (r & 3) + 8 * (r >> 2) + 4 * h8;
          int R = obase + 2 * row;               // e'_cn overwrites H_cn
          *(u32*)(eL + eaddr32(R, m31)) = pack_bf2(d0[t][r], d1[t][r]);
        }
      }
    }

    // ---- layer-2 bn ----
    {
      short8 Hb[2][4];
      #pragma unroll
      for (int t = 0; t < 2; ++t) {
        int R = 128 * w + 64 * t + 2 * m31 + 1;
        #pragma unroll
        for (int f = 0; f < 4; ++f)
          Hb[t][f] = *(const short8*)(eL + eaddr(R, f * 2 + h8));
      }
      f32x16 d0[2], d1[2];
      #pragma unroll
      for (int t = 0; t < 2; ++t)
        #pragma unroll
        for (int r = 0; r < 16; ++r) { d0[t][r] = bb2.x; d1[t][r] = bb2.y; }
      #pragma unroll
      for (int ks = 0; ks < 4; ++ks) {
        short8 B0 = BFR(40 + ks * 2 + 0);
        short8 B1 = BFR(40 + ks * 2 + 1);
        #pragma unroll
        for (int t = 0; t < 2; ++t) {
          d0[t] = __builtin_amdgcn_mfma_f32_32x32x16_bf16(Hb[t][ks], B0, d0[t], 0, 0, 0);
          d1[t] = __builtin_amdgcn_mfma_f32_32x32x16_bf16(Hb[t][ks], B1, d1[t], 0, 0, 0);
        }
      }
      #pragma unroll
      for (int t = 0; t < 2; ++t) {
        int obase = 128 * w + 64 * t;
        #pragma unroll
        for (int r = 0; r < 16; ++r) {
          int row = (r & 3) + 8 * (r >> 2) + 4 * h8;
          int R = obase + 2 * row + 1;           // e'_bn overwrites H_bn
          *(u32*)(eL + eaddr32(R, m31)) = pack_bf2(d0[t][r], d1[t][r]);
        }
      }
    }
    __syncthreads();   // e' visible to next stage
  }

  // ---------------- final epilogue (stage 10) ----------------
  {
    const uint4* lwq = (const uint4*)(wfrag + LW_OFF);
    uint4 lq[4][2];
    #pragma unroll
    for (int f = 0; f < 4; ++f) {
      lq[f][0] = lwq[f * 4 + h8 * 2];
      lq[f][1] = lwq[f * 4 + h8 * 2 + 1];
    }
    #pragma unroll
    for (int it = 0; it < 4; ++it) {
      int n = 128 * w + 32 * it + m31;
      float z0 = 0.f, z1 = 0.f, nr = 0.f;
      #pragma unroll
      for (int f = 0; f < 4; ++f) {
        short8 av8 = *(const short8*)(eL + eaddr(n, f * 2 + h8));
        #pragma unroll
        for (int j = 0; j < 8; ++j) {
          u32 pv = ((const u32*)&av8)[j >> 1];
          float val = __uint_as_float((j & 1) ? (pv & 0xffff0000u) : (pv << 16));
          u32 lwp = (j < 4) ? ((const u32*)&lq[f][0])[j] : ((const u32*)&lq[f][1])[j - 4];
          z0 = fmaf(val, __uint_as_float(lwp << 16), z0);
          z1 = fmaf(val, __uint_as_float(lwp & 0xffff0000u), z1);
          nr = fmaf(val, val, nr);
        }
      }
      z0 += __shfl_xor(z0, 32);
      z1 += __shfl_xor(z1, 32);
      nr += __shfl_xor(nr, 32);
      int lab = (vmask[0][n >> 5] >> (n & 31)) & 1;
      if (h8 == 0) emit_out(out, b, n, NSTAGES - 1, z0 + lb0, z1 + lb1, nr, lab);
    }
  }
}

extern "C" void kernel_launch(void* const* d_in, const int* in_sizes, int n_in,
                              void* d_out, int out_size, void* d_ws, size_t ws_size,
                              hipStream_t stream) {
  const int*   x      = (const int*)d_in[0];
  const float* y      = (const float*)d_in[1];
  const float* emb_W  = (const float*)d_in[2];
  const float* emb_b  = (const float*)d_in[3];
  const float* labemb = (const float*)d_in[4];
  const float* cn_W1  = (const float*)d_in[5];
  const float* cn_b1  = (const float*)d_in[6];
  const float* cn_W2  = (const float*)d_in[7];
  const float* cn_b2  = (const float*)d_in[8];
  const float* bn_W1  = (const float*)d_in[9];
  const float* bn_b1  = (const float*)d_in[10];
  const float* bn_W2  = (const float*)d_in[11];
  const float* bn_b2  = (const float*)d_in[12];
  const float* llr_W  = (const float*)d_in[13];
  const float* llr_b  = (const float*)d_in[14];
  float* out = (float*)d_out;

  u16* wfrag = (u16*)d_ws;                       // 48*512 + 64 u32 ≤ 64 KB
  float* labW_g = (float*)((char*)d_ws + 65536); // fp32[2][64]

  prep_kernel<<<13, 256, 0, stream>>>(cn_W1, bn_W1, cn_W2, bn_W2, labemb, llr_W,
                                      bn_b1, wfrag, labW_g);
  polar_kernel<<<NB, 512, 0, stream>>>(x, y, emb_W, emb_b, wfrag, labW_g,
                                       cn_b1, cn_b2, bn_b2, llr_W, llr_b, out);
}